// Round 6
// baseline (70.373 us; speedup 1.0000x reference)
//
#include <hip/hip_runtime.h>
#include <math.h>

typedef __attribute__((ext_vector_type(8))) short short8;
typedef __attribute__((ext_vector_type(4))) float f32x4;
typedef unsigned short ushort_t;
typedef unsigned int uint_t;

#define HH 128
#define WW 128
#define CC 64
#define HWp 16384

__device__ inline ushort_t f2bf(float f) {
    uint_t u = __float_as_uint(f);
    uint_t r = (u + 0x7FFFu + ((u >> 16) & 1u)) >> 16;
    return (ushort_t)r;
}
__device__ inline float blo(uint_t u) { return __uint_as_float(u << 16); }
__device__ inline float bhi(uint_t u) { return __uint_as_float(u & 0xFFFF0000u); }
__device__ inline short8 bc8(uint4 v) { return __builtin_bit_cast(short8, v); }

__device__ inline uint_t pk2(f32x4 wv, uint_t a, uint_t b, uint_t c, uint_t d) {
    float lo = wv.x * blo(a) + wv.y * blo(b) + wv.z * blo(c) + wv.w * blo(d);
    float hi = wv.x * bhi(a) + wv.y * bhi(b) + wv.z * bhi(c) + wv.w * bhi(d);
    uint_t r;
    asm("v_cvt_pk_bf16_f32 %0, %1, %2" : "=v"(r) : "v"(lo), "v"(hi));
    return r;
}
__device__ inline short8 bilerp8(f32x4 wv, uint4 A, uint4 B, uint4 C, uint4 D) {
    uint4 r;
    r.x = pk2(wv, A.x, B.x, C.x, D.x);
    r.y = pk2(wv, A.y, B.y, C.y, D.y);
    r.z = pk2(wv, A.z, B.z, C.z, D.z);
    r.w = pk2(wv, A.w, B.w, C.w, D.w);
    return __builtin_bit_cast(short8, r);
}

// ---------------- weight packing into MFMA A-fragment order -----------------
__global__ __launch_bounds__(256) void k_pack(const float* __restrict__ w_off,
        const float* __restrict__ w_mask, const float* __restrict__ w,
        ushort_t* __restrict__ wpom, ushort_t* __restrict__ wpm) {
    int idx = blockIdx.x * 256 + threadIdx.x;
    if (idx < 18432) {
        int e = idx;
        int j = e & 7, l = (e >> 3) & 63, mf = (e >> 9) & 1, ks = e >> 10;
        int ch = mf * 16 + (l & 15);
        int k = ks * 32 + ((l >> 4) << 3) + j;
        int c = k & 63, kk = k >> 6;
        float v = 0.f;
        if (ch < 18) v = w_off[(ch * CC + c) * 9 + kk];
        else if (ch < 27) v = w_mask[((ch - 18) * CC + c) * 9 + kk];
        wpom[idx] = f2bf(v);
    } else if (idx < 18432 + 36864) {
        int e = idx - 18432;
        int j = e & 7, l = (e >> 3) & 63, mf = (e >> 9) & 3, ks = e >> 11;
        int o = mf * 16 + (l & 15);
        int k = ks * 32 + ((l >> 4) << 3) + j;
        int c = k & 63, kk = k >> 6;
        wpm[e] = f2bf(w[(o * CC + c) * 9 + kk]);
    }
}

// ---------------- x: NCHW f32 -> NHWC bf16 ----------------------------------
__global__ __launch_bounds__(256) void k_transpose_x(const float* __restrict__ x,
                                                     ushort_t* __restrict__ xtb) {
    __shared__ float tile[64][65];
    int bid = blockIdx.x;
    int xs = (bid & 1) * 64;
    int y  = (bid >> 1) & 127;
    int b  = bid >> 8;
    int t = threadIdx.x, lane = t & 63, g = t >> 6;
#pragma unroll
    for (int i = 0; i < 16; ++i) {
        int c = i * 4 + g;
        tile[c][lane] = x[(((size_t)b * CC + c) * HH + y) * WW + xs + lane];
    }
    __syncthreads();
#pragma unroll
    for (int i = 0; i < 16; ++i) {
        int xx = i * 4 + g;
        xtb[(((size_t)b * HH + y) * WW + xs + xx) * CC + lane] = f2bf(tile[lane][xx]);
    }
}

// ---------------- offset/mask conv as MFMA GEMM (512 thr, 8 waves) ----------
__global__ __launch_bounds__(512, 4) void k_conv_om(const ushort_t* __restrict__ xtb,
        const uint4* __restrict__ wpom, const float* __restrict__ b_off,
        const float* __restrict__ b_mask, float* __restrict__ om) {
    __shared__ ushort_t xrow[3 * 132 * 64];   // idx ^= (col&7)<<3 swizzle
    int blk = blockIdx.x;
    int y = blk & 127, b = blk >> 7;
    int t = threadIdx.x;

    for (int ky = 0; ky < 3; ++ky) {
        int yy = y + ky - 1;
        bool ok = (yy >= 0) && (yy < HH);
#pragma unroll
        for (int i = 0; i < 2; ++i) {
            int t2 = i * 512 + t;
            int colr = t2 >> 3;
            int c0 = (t2 & 7) * 8;
            uint4 v = make_uint4(0u, 0u, 0u, 0u);
            if (ok) v = *(const uint4*)&xtb[(((size_t)b * HWp) + yy * WW + colr) * CC + c0];
            int col = colr + 1;
            int idx = ((ky * 132 + col) * 64 + c0) ^ ((col & 7) << 3);
            *(uint4*)&xrow[idx] = v;
        }
    }
    if (t < 48) {
        int ky = t >> 4, cs = (t >> 3) & 1, chn = t & 7;
        int col = cs ? 129 : 0;
        int idx = ((ky * 132 + col) * 64 + chn * 8) ^ ((col & 7) << 3);
        *(uint4*)&xrow[idx] = make_uint4(0u, 0u, 0u, 0u);
    }
    __syncthreads();

    int lane = t & 63, w = t >> 6;
    int lm = lane & 15, lg = lane >> 4;
    int px = w * 16 + lm;
    f32x4 acc[2] = {};
#pragma unroll
    for (int ks = 0; ks < 18; ++ks) {
        int kk = ks >> 1;
        int kyy = kk / 3, kxx = kk % 3;
        int c0 = (ks & 1) * 32 + lg * 8;
        short8 a0 = bc8(wpom[(ks * 2 + 0) * 64 + lane]);
        short8 a1 = bc8(wpom[(ks * 2 + 1) * 64 + lane]);
        int col = px + kxx;
        int idx = ((kyy * 132 + col) * 64 + c0) ^ ((col & 7) << 3);
        short8 bf = *(const short8*)&xrow[idx];
        acc[0] = __builtin_amdgcn_mfma_f32_16x16x32_bf16(a0, bf, acc[0], 0, 0, 0);
        acc[1] = __builtin_amdgcn_mfma_f32_16x16x32_bf16(a1, bf, acc[1], 0, 0, 0);
    }
#pragma unroll
    for (int mf = 0; mf < 2; ++mf)
#pragma unroll
        for (int r = 0; r < 4; ++r) {
            int ch = mf * 16 + lg * 4 + r;
            if (ch < 27) {
                float v = acc[mf][r] + (ch < 18 ? b_off[ch] : b_mask[ch - 18]);
                if (ch >= 18) v = 1.f / (1.f + __expf(-v));
                om[(((size_t)b * 27 + ch) << 14) + (y << 7) + px] = v;
            }
        }
}

// ---------------- fused deform-gather + main GEMM (direct-to-register) ------
// Block = one row (b, y): 128 px, 8 waves. Each wave independently owns 16 px.
// Phase 0: prm[128 px][9 taps]: 4 folded bilinear weights + 2 row-pair byte
//          offsets (one barrier, only inter-thread coupling in the kernel).
// Main loop (per tap): lane (cq=l>>4, px=l&15) loads the 2x2 corner block's
//   channel slice as 8 x dwordx4 (wave covers 16 px x 256 B dense), bilerps
//   in-register, cvt_pk -> B-frag; 8 MFMA (2 ksteps x 4 mfrags) into 16 AGPRs.
// No im2col LDS, no second barrier, no sm bank conflicts.
__global__ __launch_bounds__(512, 4) void k_fused(const ushort_t* __restrict__ xtb,
        const float* __restrict__ om, const uint4* __restrict__ wpm,
        const float* __restrict__ bias, float* __restrict__ out) {
    __shared__ __align__(16) float prm[1152 * 8];      // [px][k][8]
    int blk = blockIdx.x;                              // = b*128 + y
    int b = blk >> 7, y = blk & 127;
    int t = threadIdx.x, lane = t & 63, w = t >> 6;
    const char* xbB = (const char*)xtb + ((size_t)b << 21);
    const float* omb = om + (((size_t)b * 27) << 14) + (y << 7);

    // ---- phase 0: params for 128 px x 9 taps (coalesced om reads) ----
    for (int s = t; s < 1152; s += 512) {
        int k = s >> 7, px = s & 127;
        int ki = k / 3, kj = k - ki * 3;
        float dy = omb[((2 * k) << 14) + px];
        float dx = omb[((2 * k + 1) << 14) + px];
        float m  = omb[((18 + k) << 14) + px];
        float sy = (float)(y - 1 + ki) + dy;
        float sx = (float)(px - 1 + kj) + dx;
        float fy = floorf(sy), fx = floorf(sx);
        float wy1 = sy - fy, wx1 = sx - fx;
        float wy0 = 1.f - wy1, wx0 = 1.f - wx1;
        int iy0 = (int)fy, ix0 = (int)fx;
        int iy1 = iy0 + 1, ix1 = ix0 + 1;
        bool vy0 = (iy0 >= 0) & (iy0 < HH);
        bool vy1 = (iy1 >= 0) & (iy1 < HH);
        float wyr0 = vy0 ? wy0 : (vy1 ? wy1 : 0.f);
        int   ry0  = vy0 ? iy0 : (vy1 ? iy1 : 0);
        float wyr1 = (vy0 & vy1) ? wy1 : 0.f;
        int   ry1  = min(max(iy1, 0), HH - 1);
        int bx = min(max(ix0, 0), WW - 2);
        float wxh0 = (bx == ix0) ? wx0 : ((bx == ix1) ? wx1 : 0.f);
        float wxh1 = (bx + 1 == ix1) ? wx1 : ((bx + 1 == ix0) ? wx0 : 0.f);
        float* pp = prm + (px * 9 + k) * 8;
        pp[0] = m * wyr0 * wxh0;
        pp[1] = m * wyr0 * wxh1;
        pp[2] = m * wyr1 * wxh0;
        pp[3] = m * wyr1 * wxh1;
        pp[4] = __uint_as_float((uint_t)(((ry0 << 7) + bx) << 7));   // top byte off
        pp[5] = __uint_as_float((uint_t)(((ry1 << 7) + bx) << 7));   // bot byte off
    }
    __syncthreads();

    // ---- main loop: 16 px per wave, full K, acc in registers ----
    int lm = lane & 15, cq = lane >> 4;
    int px = (w << 4) + lm;
    uint_t cqb = (uint_t)(cq << 4);        // channel-quarter byte offset
    f32x4 acc0 = {}, acc1 = {}, acc2 = {}, acc3 = {};
#pragma unroll
    for (int k = 0; k < 9; ++k) {
        const float* pp = prm + (px * 9 + k) * 8;
        f32x4 wv = *(const f32x4*)pp;
        uint_t aT = __float_as_uint(pp[4]) + cqb;
        uint_t aB = __float_as_uint(pp[5]) + cqb;
        // kstep 0: channels 0..31 (bytes 0..63 of each pixel row)
        uint4 tl0 = *(const uint4*)(xbB + aT);
        uint4 tr0 = *(const uint4*)(xbB + aT + 128);
        uint4 bl0 = *(const uint4*)(xbB + aB);
        uint4 br0 = *(const uint4*)(xbB + aB + 128);
        // kstep 1: channels 32..63 (bytes 64..127)
        uint4 tl1 = *(const uint4*)(xbB + aT + 64);
        uint4 tr1 = *(const uint4*)(xbB + aT + 192);
        uint4 bl1 = *(const uint4*)(xbB + aB + 64);
        uint4 br1 = *(const uint4*)(xbB + aB + 192);
        short8 bf0 = bilerp8(wv, tl0, tr0, bl0, br0);
        short8 bf1 = bilerp8(wv, tl1, tr1, bl1, br1);
        int ka = (k << 3) * 64 + lane;     // (k*8 + ks*4 + mf)*64 + lane
        acc0 = __builtin_amdgcn_mfma_f32_16x16x32_bf16(bc8(wpm[ka +   0]), bf0, acc0, 0, 0, 0);
        acc1 = __builtin_amdgcn_mfma_f32_16x16x32_bf16(bc8(wpm[ka +  64]), bf0, acc1, 0, 0, 0);
        acc2 = __builtin_amdgcn_mfma_f32_16x16x32_bf16(bc8(wpm[ka + 128]), bf0, acc2, 0, 0, 0);
        acc3 = __builtin_amdgcn_mfma_f32_16x16x32_bf16(bc8(wpm[ka + 192]), bf0, acc3, 0, 0, 0);
        acc0 = __builtin_amdgcn_mfma_f32_16x16x32_bf16(bc8(wpm[ka + 256]), bf1, acc0, 0, 0, 0);
        acc1 = __builtin_amdgcn_mfma_f32_16x16x32_bf16(bc8(wpm[ka + 320]), bf1, acc1, 0, 0, 0);
        acc2 = __builtin_amdgcn_mfma_f32_16x16x32_bf16(bc8(wpm[ka + 384]), bf1, acc2, 0, 0, 0);
        acc3 = __builtin_amdgcn_mfma_f32_16x16x32_bf16(bc8(wpm[ka + 448]), bf1, acc3, 0, 0, 0);
    }

    // ---- epilogue: D col = px (lane&15), row = cq*4 + r ----
    size_t obase = ((size_t)b << 20) + (y << 7) + px;    // + o*16384
#pragma unroll
    for (int r = 0; r < 4; ++r) {
        int o0 = cq * 4 + r;
        out[obase + (size_t)(o0     ) * HWp] = acc0[r] + bias[o0];
        out[obase + (size_t)(o0 + 16) * HWp] = acc1[r] + bias[o0 + 16];
        out[obase + (size_t)(o0 + 32) * HWp] = acc2[r] + bias[o0 + 32];
        out[obase + (size_t)(o0 + 48) * HWp] = acc3[r] + bias[o0 + 48];
    }
}

extern "C" void kernel_launch(void* const* d_in, const int* in_sizes, int n_in,
                              void* d_out, int out_size, void* d_ws, size_t ws_size,
                              hipStream_t stream) {
    const float* x      = (const float*)d_in[0];
    const float* w_off  = (const float*)d_in[1];
    const float* b_off  = (const float*)d_in[2];
    const float* w_mask = (const float*)d_in[3];
    const float* b_mask = (const float*)d_in[4];
    const float* w      = (const float*)d_in[5];
    const float* bias   = (const float*)d_in[6];
    float* out = (float*)d_out;

    char* ws = (char*)d_ws;
    ushort_t* xtb  = (ushort_t*)(ws);                    //  8,388,608 B
    float*    om   = (float*)(ws + 8388608);             //  7,077,888 B
    ushort_t* wpom = (ushort_t*)(ws + 15466496);         //     36,864 B
    ushort_t* wpm  = (ushort_t*)(ws + 15503360);         //     73,728 B

    hipLaunchKernelGGL(k_pack, dim3(216), dim3(256), 0, stream,
                       w_off, w_mask, w, wpom, wpm);
    hipLaunchKernelGGL(k_transpose_x, dim3(1024), dim3(256), 0, stream, x, xtb);
    hipLaunchKernelGGL(k_conv_om, dim3(512), dim3(512), 0, stream,
                       xtb, (const uint4*)wpom, b_off, b_mask, om);
    hipLaunchKernelGGL(k_fused, dim3(512), dim3(512), 0, stream,
                       xtb, om, (const uint4*)wpm, bias, out);
}

// Round 7
// 54.763 us; speedup vs baseline: 1.2851x; 1.2851x over previous
//
#include <hip/hip_runtime.h>
#include <math.h>

typedef __attribute__((ext_vector_type(8))) short short8;
typedef __attribute__((ext_vector_type(4))) float f32x4;
typedef unsigned short ushort_t;
typedef unsigned int uint_t;

#define HH 128
#define WW 128
#define CC 64
#define HWp 16384

__device__ inline ushort_t f2bf(float f) {
    uint_t u = __float_as_uint(f);
    uint_t r = (u + 0x7FFFu + ((u >> 16) & 1u)) >> 16;
    return (ushort_t)r;
}
__device__ inline float blo(uint_t u) { return __uint_as_float(u << 16); }
__device__ inline float bhi(uint_t u) { return __uint_as_float(u & 0xFFFF0000u); }
__device__ inline short8 bc8(uint4 v) { return __builtin_bit_cast(short8, v); }

__device__ inline uint_t pk2(f32x4 wv, uint_t a, uint_t b, uint_t c, uint_t d) {
    float lo = wv.x * blo(a) + wv.y * blo(b) + wv.z * blo(c) + wv.w * blo(d);
    float hi = wv.x * bhi(a) + wv.y * bhi(b) + wv.z * bhi(c) + wv.w * bhi(d);
    uint_t r;
    asm("v_cvt_pk_bf16_f32 %0, %1, %2" : "=v"(r) : "v"(lo), "v"(hi));
    return r;
}
__device__ inline short8 bilerp8(f32x4 wv, uint4 A, uint4 B, uint4 C, uint4 D) {
    uint4 r;
    r.x = pk2(wv, A.x, B.x, C.x, D.x);
    r.y = pk2(wv, A.y, B.y, C.y, D.y);
    r.z = pk2(wv, A.z, B.z, C.z, D.z);
    r.w = pk2(wv, A.w, B.w, C.w, D.w);
    return __builtin_bit_cast(short8, r);
}

// ---------------- weight packing into MFMA A-fragment order -----------------
__global__ __launch_bounds__(256) void k_pack(const float* __restrict__ w_off,
        const float* __restrict__ w_mask, const float* __restrict__ w,
        ushort_t* __restrict__ wpom, ushort_t* __restrict__ wpm) {
    int idx = blockIdx.x * 256 + threadIdx.x;
    if (idx < 18432) {
        int e = idx;
        int j = e & 7, l = (e >> 3) & 63, mf = (e >> 9) & 1, ks = e >> 10;
        int ch = mf * 16 + (l & 15);
        int k = ks * 32 + ((l >> 4) << 3) + j;
        int c = k & 63, kk = k >> 6;
        float v = 0.f;
        if (ch < 18) v = w_off[(ch * CC + c) * 9 + kk];
        else if (ch < 27) v = w_mask[((ch - 18) * CC + c) * 9 + kk];
        wpom[idx] = f2bf(v);
    } else if (idx < 18432 + 36864) {
        int e = idx - 18432;
        int j = e & 7, l = (e >> 3) & 63, mf = (e >> 9) & 3, ks = e >> 11;
        int o = mf * 16 + (l & 15);
        int k = ks * 32 + ((l >> 4) << 3) + j;
        int c = k & 63, kk = k >> 6;
        wpm[e] = f2bf(w[(o * CC + c) * 9 + kk]);
    }
}

// ---------------- x: NCHW f32 -> NHWC bf16 (vectorized) ---------------------
__global__ __launch_bounds__(256) void k_transpose_x(const float* __restrict__ x,
                                                     ushort_t* __restrict__ xtb) {
    __shared__ __align__(16) float tile[64][68];
    int bid = blockIdx.x;
    int xs = (bid & 1) * 64;
    int y  = (bid >> 1) & 127;
    int b  = bid >> 8;
    int t = threadIdx.x;
#pragma unroll
    for (int i = 0; i < 4; ++i) {
        int c  = i * 16 + (t >> 4);
        int xl = (t & 15) << 2;
        float4 v = *(const float4*)&x[(((size_t)b * CC + c) * HH + y) * WW + xs + xl];
        *(float4*)&tile[c][xl] = v;
    }
    __syncthreads();
#pragma unroll
    for (int i = 0; i < 8; ++i) {
        int pxl = i * 8 + (t >> 5);
        int cp  = t & 31;
        float v0 = tile[cp * 2][pxl], v1 = tile[cp * 2 + 1][pxl];
        uint_t pk;
        asm("v_cvt_pk_bf16_f32 %0, %1, %2" : "=v"(pk) : "v"(v0), "v"(v1));
        *(uint_t*)&xtb[(((size_t)b * HH + y) * WW + xs + pxl) * CC + cp * 2] = pk;
    }
}

// ---------------- offset/mask conv as MFMA GEMM (64 px, 256 thr) ------------
__global__ __launch_bounds__(256, 4) void k_conv_om(const ushort_t* __restrict__ xtb,
        const uint4* __restrict__ wpom, const float* __restrict__ b_off,
        const float* __restrict__ b_mask, float* __restrict__ om) {
    __shared__ ushort_t xrow[3 * 68 * 64];    // idx ^= (cl&7)<<3 swizzle
    int blk = blockIdx.x;                      // 1024
    int b = blk >> 8, rem = blk & 255;
    int y = rem >> 1, xh = (rem & 1) * 64;
    int t = threadIdx.x;

    for (int ky = 0; ky < 3; ++ky) {
        int yy = y + ky - 1;
        bool rok = (yy >= 0) && (yy < HH);
#pragma unroll
        for (int i = 0; i < 3; ++i) {
            int t2 = i * 256 + t;
            if (t2 < 528) {                    // 66 cols x 8 chunks
                int cl = t2 >> 3;              // 0..65, x = xh-1+cl
                int c0 = (t2 & 7) * 8;
                int xcoord = xh - 1 + cl;
                bool ok = rok && (xcoord >= 0) && (xcoord < WW);
                uint4 v = make_uint4(0u, 0u, 0u, 0u);
                if (ok) v = *(const uint4*)&xtb[(((size_t)b * HWp) + yy * WW + xcoord) * CC + c0];
                int idx = ((ky * 68 + cl) * 64 + c0) ^ ((cl & 7) << 3);
                *(uint4*)&xrow[idx] = v;
            }
        }
    }
    __syncthreads();

    int lane = t & 63, w = t >> 6;             // 4 waves
    int lm = lane & 15, lg = lane >> 4;
    int pxl = w * 16 + lm;                     // 0..63 local
    f32x4 acc[2] = {};
#pragma unroll
    for (int ks = 0; ks < 18; ++ks) {
        int kk = ks >> 1;
        int kyy = kk / 3, kxx = kk % 3;
        int c0 = (ks & 1) * 32 + lg * 8;
        short8 a0 = bc8(wpom[(ks * 2 + 0) * 64 + lane]);
        short8 a1 = bc8(wpom[(ks * 2 + 1) * 64 + lane]);
        int cl = pxl + kxx;
        int idx = ((kyy * 68 + cl) * 64 + c0) ^ ((cl & 7) << 3);
        short8 bf = *(const short8*)&xrow[idx];
        acc[0] = __builtin_amdgcn_mfma_f32_16x16x32_bf16(a0, bf, acc[0], 0, 0, 0);
        acc[1] = __builtin_amdgcn_mfma_f32_16x16x32_bf16(a1, bf, acc[1], 0, 0, 0);
    }
    int px = xh + pxl;
#pragma unroll
    for (int mf = 0; mf < 2; ++mf)
#pragma unroll
        for (int r = 0; r < 4; ++r) {
            int ch = mf * 16 + lg * 4 + r;
            if (ch < 27) {
                float v = acc[mf][r] + (ch < 18 ? b_off[ch] : b_mask[ch - 18]);
                if (ch >= 18) v = 1.f / (1.f + __expf(-v));
                om[(((size_t)b * 27 + ch) << 14) + (y << 7) + px] = v;
            }
        }
}

// ---------------- fused deform-gather + main GEMM (32 px, 512 thr) ----------
// Phase 0: per-(k,px) params: 4 folded weights, 2 row-pair byte offsets,
//          sm write base + swizzle.
// Phase 1: 8-lane group = one sample, 8 ch/lane via dwordx4; all aux preloaded
//          to registers, corner loads software-pipelined one round ahead.
// Phase 2: MFMA, wave = (mfrag, n-half).
__global__ __launch_bounds__(512, 6) void k_fused(const ushort_t* __restrict__ xtb,
        const float* __restrict__ om, const uint4* __restrict__ wpm,
        const float* __restrict__ bias, float* __restrict__ out) {
    __shared__ __align__(16) ushort_t sm[32 * 576];    // idx ^= ((px^k)&7)<<3
    __shared__ __align__(16) float prm[288 * 8];       // [s = px*9+k][8]
    int blk = blockIdx.x;
    int b = blk >> 9, rem = blk & 511;
    int y = rem >> 2, xs = (rem & 3) * 32;
    int t = threadIdx.x, lane = t & 63, w = t >> 6;
    const char* xbB = (const char*)xtb + ((size_t)b << 21);
    const float* omb = om + (((size_t)b * 27) << 14) + (y << 7) + xs;

    // ---- phase 0 (t = [k][px] for coalesced om reads) ----
    if (t < 288) {
        int k = t >> 5, px = t & 31;
        int ki = k / 3, kj = k - ki * 3;
        int x = xs + px;
        float dy = omb[((2 * k) << 14) + px];
        float dx = omb[((2 * k + 1) << 14) + px];
        float m  = omb[((18 + k) << 14) + px];
        float sy = (float)(y - 1 + ki) + dy;
        float sx = (float)(x - 1 + kj) + dx;
        float fy = floorf(sy), fx = floorf(sx);
        float wy1 = sy - fy, wx1 = sx - fx;
        float wy0 = 1.f - wy1, wx0 = 1.f - wx1;
        int iy0 = (int)fy, ix0 = (int)fx;
        int iy1 = iy0 + 1, ix1 = ix0 + 1;
        bool vy0 = (iy0 >= 0) & (iy0 < HH);
        bool vy1 = (iy1 >= 0) & (iy1 < HH);
        float wyr0 = vy0 ? wy0 : (vy1 ? wy1 : 0.f);
        int   ry0  = vy0 ? iy0 : (vy1 ? iy1 : 0);
        float wyr1 = (vy0 & vy1) ? wy1 : 0.f;
        int   ry1  = min(max(iy1, 0), HH - 1);
        int bx = min(max(ix0, 0), WW - 2);
        float wxh0 = (bx == ix0) ? wx0 : ((bx == ix1) ? wx1 : 0.f);
        float wxh1 = (bx + 1 == ix1) ? wx1 : ((bx + 1 == ix0) ? wx0 : 0.f);
        int s = px * 9 + k;
        float* pp = prm + s * 8;
        pp[0] = m * wyr0 * wxh0;
        pp[1] = m * wyr0 * wxh1;
        pp[2] = m * wyr1 * wxh0;
        pp[3] = m * wyr1 * wxh1;
        pp[4] = __uint_as_float((uint_t)(((ry0 << 7) + bx) << 7));   // top byte off
        pp[5] = __uint_as_float((uint_t)(((ry1 << 7) + bx) << 7));   // bot byte off
        pp[6] = __uint_as_float((uint_t)(px * 576 + k * 64));        // sm ushort base
        pp[7] = __uint_as_float((uint_t)(((px ^ k) & 7) << 3));      // swizzle
    }
    __syncthreads();

    // ---- phase 1: 8-lane group = 1 sample, 8 ch/lane, pipelined ----
    {
        int g = lane >> 3, j = lane & 7;
        uint_t j16 = (uint_t)(j << 4);         // byte offset within 128 B row
        uint_t jw  = (uint_t)(j << 3);         // ushort offset within sm row
        int s0 = w * 36 + g;
        uint4 axv[5];
#pragma unroll
        for (int r = 0; r < 5; ++r) {
            int s = s0 + r * 8; s = s > 287 ? 287 : s;
            axv[r] = *(const uint4*)(prm + s * 8 + 4);
        }
        uint4 tlA, trA, blA, brA, tlB, trB, blB, brB;
        {
            uint_t aT = axv[0].x + j16, aB = axv[0].y + j16;
            tlA = *(const uint4*)(xbB + aT);  trA = *(const uint4*)(xbB + aT + 128);
            blA = *(const uint4*)(xbB + aB);  brA = *(const uint4*)(xbB + aB + 128);
        }
#pragma unroll
        for (int r = 0; r < 5; ++r) {
            if (r < 4) {
                uint_t aT = axv[r + 1].x + j16, aB = axv[r + 1].y + j16;
                tlB = *(const uint4*)(xbB + aT);  trB = *(const uint4*)(xbB + aT + 128);
                blB = *(const uint4*)(xbB + aB);  brB = *(const uint4*)(xbB + aB + 128);
            }
            int s = s0 + r * 8; s = s > 287 ? 287 : s;
            f32x4 wv = *(const f32x4*)(prm + s * 8);
            short8 bf = bilerp8(wv, tlA, trA, blA, brA);
            if (r < 4 || g < 4) {
                uint_t widx = (axv[r].z + jw) ^ axv[r].w;
                *(short8*)&sm[widx] = bf;
            }
            tlA = tlB; trA = trB; blA = blB; brA = brB;
        }
    }
    __syncthreads();

    // ---- phase 2: out[64 x 32] = W(64x576) . sm(576x32), 8 waves ----
    int lm = lane & 15, lg = lane >> 4;
    int mf = w & 3, nh = w >> 2;
    int px_r = (nh << 4) + lm;
    f32x4 acc = {};
#pragma unroll
    for (int ks = 0; ks < 18; ++ks) {
        short8 af = bc8(wpm[((ks << 2) + mf) * 64 + lane]);
        int bidx = (px_r * 576 + (ks << 5) + (lg << 3)) ^ (((px_r ^ (ks >> 1)) & 7) << 3);
        short8 bf = *(const short8*)&sm[bidx];
        acc = __builtin_amdgcn_mfma_f32_16x16x32_bf16(af, bf, acc, 0, 0, 0);
    }
#pragma unroll
    for (int r = 0; r < 4; ++r) {
        int o = (mf << 4) + (lg << 2) + r;
        out[(((size_t)b * 64 + o) << 14) + (y << 7) + xs + px_r] = acc[r] + bias[o];
    }
}

extern "C" void kernel_launch(void* const* d_in, const int* in_sizes, int n_in,
                              void* d_out, int out_size, void* d_ws, size_t ws_size,
                              hipStream_t stream) {
    const float* x      = (const float*)d_in[0];
    const float* w_off  = (const float*)d_in[1];
    const float* b_off  = (const float*)d_in[2];
    const float* w_mask = (const float*)d_in[3];
    const float* b_mask = (const float*)d_in[4];
    const float* w      = (const float*)d_in[5];
    const float* bias   = (const float*)d_in[6];
    float* out = (float*)d_out;

    char* ws = (char*)d_ws;
    ushort_t* xtb  = (ushort_t*)(ws);                    //  8,388,608 B
    float*    om   = (float*)(ws + 8388608);             //  7,077,888 B
    ushort_t* wpom = (ushort_t*)(ws + 15466496);         //     36,864 B
    ushort_t* wpm  = (ushort_t*)(ws + 15503360);         //     73,728 B

    hipLaunchKernelGGL(k_pack, dim3(216), dim3(256), 0, stream,
                       w_off, w_mask, w, wpom, wpm);
    hipLaunchKernelGGL(k_transpose_x, dim3(1024), dim3(256), 0, stream, x, xtb);
    hipLaunchKernelGGL(k_conv_om, dim3(1024), dim3(256), 0, stream,
                       xtb, (const uint4*)wpom, b_off, b_mask, om);
    hipLaunchKernelGGL(k_fused, dim3(2048), dim3(512), 0, stream,
                       xtb, om, (const uint4*)wpm, bias, out);
}

// Round 8
// 50.595 us; speedup vs baseline: 1.3909x; 1.0824x over previous
//
#include <hip/hip_runtime.h>
#include <math.h>

typedef __attribute__((ext_vector_type(8))) short short8;
typedef __attribute__((ext_vector_type(4))) float f32x4;
typedef unsigned short ushort_t;
typedef unsigned int uint_t;

#define HH 128
#define WW 128
#define CC 64
#define HWp 16384

__device__ inline ushort_t f2bf(float f) {
    uint_t u = __float_as_uint(f);
    uint_t r = (u + 0x7FFFu + ((u >> 16) & 1u)) >> 16;
    return (ushort_t)r;
}
__device__ inline float blo(uint_t u) { return __uint_as_float(u << 16); }
__device__ inline float bhi(uint_t u) { return __uint_as_float(u & 0xFFFF0000u); }
__device__ inline short8 bc8(uint4 v) { return __builtin_bit_cast(short8, v); }

__device__ inline uint_t pk2(f32x4 wv, uint_t a, uint_t b, uint_t c, uint_t d) {
    float lo = wv.x * blo(a) + wv.y * blo(b) + wv.z * blo(c) + wv.w * blo(d);
    float hi = wv.x * bhi(a) + wv.y * bhi(b) + wv.z * bhi(c) + wv.w * bhi(d);
    uint_t r;
    asm("v_cvt_pk_bf16_f32 %0, %1, %2" : "=v"(r) : "v"(lo), "v"(hi));
    return r;
}
__device__ inline short8 bilerp8(f32x4 wv, uint4 A, uint4 B, uint4 C, uint4 D) {
    uint4 r;
    r.x = pk2(wv, A.x, B.x, C.x, D.x);
    r.y = pk2(wv, A.y, B.y, C.y, D.y);
    r.z = pk2(wv, A.z, B.z, C.z, D.z);
    r.w = pk2(wv, A.w, B.w, C.w, D.w);
    return __builtin_bit_cast(short8, r);
}

// ---------------- prep: x transpose (blocks 0..1023) + weight pack ----------
__global__ __launch_bounds__(256) void k_prep(const float* __restrict__ x,
        ushort_t* __restrict__ xtb,
        const float* __restrict__ w_off, const float* __restrict__ w_mask,
        const float* __restrict__ w,
        ushort_t* __restrict__ wpom, ushort_t* __restrict__ wpm) {
    __shared__ __align__(16) float tile[64][68];
    int bid = blockIdx.x;
    int t = threadIdx.x;
    if (bid < 1024) {
        int xs = (bid & 1) * 64;
        int y  = (bid >> 1) & 127;
        int b  = bid >> 8;
#pragma unroll
        for (int i = 0; i < 4; ++i) {
            int c  = i * 16 + (t >> 4);
            int xl = (t & 15) << 2;
            float4 v = *(const float4*)&x[(((size_t)b * CC + c) * HH + y) * WW + xs + xl];
            *(float4*)&tile[c][xl] = v;
        }
        __syncthreads();
#pragma unroll
        for (int i = 0; i < 8; ++i) {
            int pxl = i * 8 + (t >> 5);
            int cp  = t & 31;
            float v0 = tile[cp * 2][pxl], v1 = tile[cp * 2 + 1][pxl];
            uint_t pk;
            asm("v_cvt_pk_bf16_f32 %0, %1, %2" : "=v"(pk) : "v"(v0), "v"(v1));
            *(uint_t*)&xtb[(((size_t)b * HH + y) * WW + xs + pxl) * CC + cp * 2] = pk;
        }
    } else {
        int idx = (bid - 1024) * 256 + t;
        if (idx < 18432) {
            int e = idx;
            int j = e & 7, l = (e >> 3) & 63, mf = (e >> 9) & 1, ks = e >> 10;
            int ch = mf * 16 + (l & 15);
            int k = ks * 32 + ((l >> 4) << 3) + j;
            int c = k & 63, kk = k >> 6;
            float v = 0.f;
            if (ch < 18) v = w_off[(ch * CC + c) * 9 + kk];
            else if (ch < 27) v = w_mask[((ch - 18) * CC + c) * 9 + kk];
            wpom[idx] = f2bf(v);
        } else if (idx < 18432 + 36864) {
            int e = idx - 18432;
            int j = e & 7, l = (e >> 3) & 63, mf = (e >> 9) & 3, ks = e >> 11;
            int o = mf * 16 + (l & 15);
            int k = ks * 32 + ((l >> 4) << 3) + j;
            int c = k & 63, kk = k >> 6;
            wpm[e] = f2bf(w[(o * CC + c) * 9 + kk]);
        }
    }
}

// ---------------- offset/mask conv as MFMA GEMM (64 px, 256 thr) ------------
__global__ __launch_bounds__(256, 4) void k_conv_om(const ushort_t* __restrict__ xtb,
        const uint4* __restrict__ wpom, const float* __restrict__ b_off,
        const float* __restrict__ b_mask, float* __restrict__ om) {
    __shared__ ushort_t xrow[3 * 68 * 64];    // idx ^= (cl&7)<<3 swizzle
    int blk = blockIdx.x;                      // 1024
    int b = blk >> 8, rem = blk & 255;
    int y = rem >> 1, xh = (rem & 1) * 64;
    int t = threadIdx.x;

    for (int ky = 0; ky < 3; ++ky) {
        int yy = y + ky - 1;
        bool rok = (yy >= 0) && (yy < HH);
#pragma unroll
        for (int i = 0; i < 3; ++i) {
            int t2 = i * 256 + t;
            if (t2 < 528) {                    // 66 cols x 8 chunks
                int cl = t2 >> 3;              // 0..65, x = xh-1+cl
                int c0 = (t2 & 7) * 8;
                int xcoord = xh - 1 + cl;
                bool ok = rok && (xcoord >= 0) && (xcoord < WW);
                uint4 v = make_uint4(0u, 0u, 0u, 0u);
                if (ok) v = *(const uint4*)&xtb[(((size_t)b * HWp) + yy * WW + xcoord) * CC + c0];
                int idx = ((ky * 68 + cl) * 64 + c0) ^ ((cl & 7) << 3);
                *(uint4*)&xrow[idx] = v;
            }
        }
    }
    __syncthreads();

    int lane = t & 63, w = t >> 6;             // 4 waves
    int lm = lane & 15, lg = lane >> 4;
    int pxl = w * 16 + lm;                     // 0..63 local
    f32x4 acc[2] = {};
#pragma unroll
    for (int ks = 0; ks < 18; ++ks) {
        int kk = ks >> 1;
        int kyy = kk / 3, kxx = kk % 3;
        int c0 = (ks & 1) * 32 + lg * 8;
        short8 a0 = bc8(wpom[(ks * 2 + 0) * 64 + lane]);
        short8 a1 = bc8(wpom[(ks * 2 + 1) * 64 + lane]);
        int cl = pxl + kxx;
        int idx = ((kyy * 68 + cl) * 64 + c0) ^ ((cl & 7) << 3);
        short8 bf = *(const short8*)&xrow[idx];
        acc[0] = __builtin_amdgcn_mfma_f32_16x16x32_bf16(a0, bf, acc[0], 0, 0, 0);
        acc[1] = __builtin_amdgcn_mfma_f32_16x16x32_bf16(a1, bf, acc[1], 0, 0, 0);
    }
    int px = xh + pxl;
#pragma unroll
    for (int mf = 0; mf < 2; ++mf)
#pragma unroll
        for (int r = 0; r < 4; ++r) {
            int ch = mf * 16 + lg * 4 + r;
            if (ch < 27) {
                float v = acc[mf][r] + (ch < 18 ? b_off[ch] : b_mask[ch - 18]);
                if (ch >= 18) v = 1.f / (1.f + __expf(-v));
                om[(((size_t)b * 27 + ch) << 14) + (y << 7) + px] = v;
            }
        }
}

// ---------------- fused deform-gather + main GEMM (32 px, 512 thr) ----------
// Phase 0 (wave-local, NO block barrier): lanes 0..35 compute the wave's own
//   4 px x 9 taps params into a private prm slice; wave-level lgkmcnt drain.
// Phase 1: 8-lane group = one sample, 8 ch/lane via dwordx4, pipelined 1 ahead.
// Phase 2: single __syncthreads, then MFMA (wave = (mfrag, n-half)).
__global__ __launch_bounds__(512, 6) void k_fused(const ushort_t* __restrict__ xtb,
        const float* __restrict__ om, const uint4* __restrict__ wpm,
        const float* __restrict__ bias, float* __restrict__ out) {
    __shared__ __align__(16) ushort_t sm[32 * 576];    // idx ^= ((px^k)&7)<<3
    __shared__ __align__(16) float prm[288 * 8];       // [wave][sl=pxl*9+k][8]
    int blk = blockIdx.x;
    int b = blk >> 9, rem = blk & 511;
    int y = rem >> 2, xs = (rem & 3) * 32;
    int t = threadIdx.x, lane = t & 63, w = t >> 6;
    const char* xbB = (const char*)xtb + ((size_t)b << 21);
    const float* omb = om + (((size_t)b * 27) << 14) + (y << 7) + xs;
    float* wprm = prm + w * (36 * 8);

    // ---- phase 0: wave-local params (lanes 0..35; 4 px x 9 taps) ----
    if (lane < 36) {
        int pxl = lane / 9, k = lane - pxl * 9;
        int px = (w << 2) + pxl;               // 0..31 in tile
        int ki = k / 3, kj = k - ki * 3;
        int x = xs + px;
        float dy = omb[((2 * k) << 14) + px];
        float dx = omb[((2 * k + 1) << 14) + px];
        float m  = omb[((18 + k) << 14) + px];
        float sy = (float)(y - 1 + ki) + dy;
        float sx = (float)(x - 1 + kj) + dx;
        float fy = floorf(sy), fx = floorf(sx);
        float wy1 = sy - fy, wx1 = sx - fx;
        float wy0 = 1.f - wy1, wx0 = 1.f - wx1;
        int iy0 = (int)fy, ix0 = (int)fx;
        int iy1 = iy0 + 1, ix1 = ix0 + 1;
        bool vy0 = (iy0 >= 0) & (iy0 < HH);
        bool vy1 = (iy1 >= 0) & (iy1 < HH);
        float wyr0 = vy0 ? wy0 : (vy1 ? wy1 : 0.f);
        int   ry0  = vy0 ? iy0 : (vy1 ? iy1 : 0);
        float wyr1 = (vy0 & vy1) ? wy1 : 0.f;
        int   ry1  = min(max(iy1, 0), HH - 1);
        int bx = min(max(ix0, 0), WW - 2);
        float wxh0 = (bx == ix0) ? wx0 : ((bx == ix1) ? wx1 : 0.f);
        float wxh1 = (bx + 1 == ix1) ? wx1 : ((bx + 1 == ix0) ? wx0 : 0.f);
        f32x4 wv4 = { m * wyr0 * wxh0, m * wyr0 * wxh1,
                      m * wyr1 * wxh0, m * wyr1 * wxh1 };
        f32x4 aux;
        aux.x = __uint_as_float((uint_t)(((ry0 << 7) + bx) << 7));   // top byte off
        aux.y = __uint_as_float((uint_t)(((ry1 << 7) + bx) << 7));   // bot byte off
        aux.z = __uint_as_float((uint_t)(px * 576 + k * 64));        // sm ushort base
        aux.w = __uint_as_float((uint_t)(((px ^ k) & 7) << 3));      // swizzle
        float* pp = wprm + lane * 8;
        *(f32x4*)pp = wv4;
        *(f32x4*)(pp + 4) = aux;
    }
    // wave-local visibility: drain LDS, forbid motion across
    asm volatile("s_waitcnt lgkmcnt(0)" ::: "memory");
    __builtin_amdgcn_sched_barrier(0);

    // ---- phase 1: 8-lane group = 1 sample, 8 ch/lane, pipelined ----
    {
        int g = lane >> 3, j = lane & 7;
        uint_t j16 = (uint_t)(j << 4);         // byte offset within 128 B row
        uint_t jw  = (uint_t)(j << 3);         // ushort offset within sm row
        uint4 axv[5];
#pragma unroll
        for (int r = 0; r < 5; ++r) {
            int sl = g + r * 8; sl = sl > 35 ? 35 : sl;
            axv[r] = *(const uint4*)(wprm + sl * 8 + 4);
        }
        uint4 tlA, trA, blA, brA, tlB, trB, blB, brB;
        {
            uint_t aT = axv[0].x + j16, aB = axv[0].y + j16;
            tlA = *(const uint4*)(xbB + aT);  trA = *(const uint4*)(xbB + aT + 128);
            blA = *(const uint4*)(xbB + aB);  brA = *(const uint4*)(xbB + aB + 128);
        }
#pragma unroll
        for (int r = 0; r < 5; ++r) {
            if (r < 4) {
                uint_t aT = axv[r + 1].x + j16, aB = axv[r + 1].y + j16;
                tlB = *(const uint4*)(xbB + aT);  trB = *(const uint4*)(xbB + aT + 128);
                blB = *(const uint4*)(xbB + aB);  brB = *(const uint4*)(xbB + aB + 128);
            }
            int sl = g + r * 8; sl = sl > 35 ? 35 : sl;
            f32x4 wv = *(const f32x4*)(wprm + sl * 8);
            short8 bf = bilerp8(wv, tlA, trA, blA, brA);
            if (r < 4 || g < 4) {
                uint_t widx = (axv[r].z + jw) ^ axv[r].w;
                *(short8*)&sm[widx] = bf;
            }
            tlA = tlB; trA = trB; blA = blB; brA = brB;
        }
    }
    __syncthreads();

    // ---- phase 2: out[64 x 32] = W(64x576) . sm(576x32), 8 waves ----
    int lm = lane & 15, lg = lane >> 4;
    int mf = w & 3, nh = w >> 2;
    int px_r = (nh << 4) + lm;
    f32x4 acc = {};
#pragma unroll
    for (int ks = 0; ks < 18; ++ks) {
        short8 af = bc8(wpm[((ks << 2) + mf) * 64 + lane]);
        int bidx = (px_r * 576 + (ks << 5) + (lg << 3)) ^ (((px_r ^ (ks >> 1)) & 7) << 3);
        short8 bf = *(const short8*)&sm[bidx];
        acc = __builtin_amdgcn_mfma_f32_16x16x32_bf16(af, bf, acc, 0, 0, 0);
    }
#pragma unroll
    for (int r = 0; r < 4; ++r) {
        int o = (mf << 4) + (lg << 2) + r;
        out[(((size_t)b * 64 + o) << 14) + (y << 7) + xs + px_r] = acc[r] + bias[o];
    }
}

extern "C" void kernel_launch(void* const* d_in, const int* in_sizes, int n_in,
                              void* d_out, int out_size, void* d_ws, size_t ws_size,
                              hipStream_t stream) {
    const float* x      = (const float*)d_in[0];
    const float* w_off  = (const float*)d_in[1];
    const float* b_off  = (const float*)d_in[2];
    const float* w_mask = (const float*)d_in[3];
    const float* b_mask = (const float*)d_in[4];
    const float* w      = (const float*)d_in[5];
    const float* bias   = (const float*)d_in[6];
    float* out = (float*)d_out;

    char* ws = (char*)d_ws;
    ushort_t* xtb  = (ushort_t*)(ws);                    //  8,388,608 B
    float*    om   = (float*)(ws + 8388608);             //  7,077,888 B
    ushort_t* wpom = (ushort_t*)(ws + 15466496);         //     36,864 B
    ushort_t* wpm  = (ushort_t*)(ws + 15503360);         //     73,728 B

    hipLaunchKernelGGL(k_prep, dim3(1240), dim3(256), 0, stream,
                       x, xtb, w_off, w_mask, w, wpom, wpm);
    hipLaunchKernelGGL(k_conv_om, dim3(1024), dim3(256), 0, stream,
                       xtb, (const uint4*)wpom, b_off, b_mask, om);
    hipLaunchKernelGGL(k_fused, dim3(2048), dim3(512), 0, stream,
                       xtb, om, (const uint4*)wpm, bias, out);
}